// Round 9
// baseline (325.113 us; speedup 1.0000x reference)
//
#include <hip/hip_runtime.h>
#include <math.h>
#include <cstdint>
#include <cstddef>

// ---------------------------------------------------------------------------
// Transformer-XL relative multihead attention, MI355X (gfx950)
// S=1024, M=1024, T=2048, B=4, D=1024, H=16, DH=64
// R17 == R16 resubmitted (round-8 bench failed at infra level: "container
// failed twice", no profile; kernel re-audited for hang/fault hazards, none
// found — no spin loops, no inter-block deps, bounds/barriers verified).
// R16: k_attn is LDS-throughput-bound (per-pipe arithmetic: ~4.3k LDS cycles
//      per block-tile ~= measured 4.4k). Restructure: 4 waves x 32 q-rows
//      (256 thr), group g = wave*2+hi keeps ALL geometry (ring, windows,
//      barriers, masks) identical to the proven R8 code. K/V fragment reads
//      shared across the 2 row-sets (1 read -> 2 MFMAs); E-window union of
//      6 tiles serves both sets (12 reads vs 20). b128/block-tile 248->152.
//      LDS unchanged 67584B -> 2 blocks/CU; VGPR ~216 under 256 cap
//      (launch_bounds(256,2)). setprio(1) around MFMA clusters (T5).
//      All other kernels unchanged from R15.
// ---------------------------------------------------------------------------

typedef _Float16 half_t;
typedef _Float16 half8 __attribute__((ext_vector_type(8)));
typedef _Float16 half4v __attribute__((ext_vector_type(4)));
typedef float f32x4 __attribute__((ext_vector_type(4)));

#define S_LEN 1024
#define M_LEN 1024
#define T_LEN 2048
#define BATCH 4
#define NHEAD 16

__device__ inline void async_copy16(const half_t* g, half_t* l) {
  __builtin_amdgcn_global_load_lds(
      (const __attribute__((address_space(1))) void*)g,
      (__attribute__((address_space(3))) void*)l, 16, 0, 0);
}

// ---- fused pre-pass: convert (b-major cbf | posb) + weight transposes -----
__global__ __launch_bounds__(256) void k_pre(const float* __restrict__ mem,
                                             const float* __restrict__ x,
                                             const float* __restrict__ pos,
                                             const float* __restrict__ Wqkv,
                                             const float* __restrict__ Wrel,
                                             const float* __restrict__ Wo,
                                             half_t* __restrict__ cbf,
                                             half_t* __restrict__ posb,
                                             half_t* __restrict__ wqkvT,
                                             half_t* __restrict__ wrelT,
                                             half_t* __restrict__ woT) {
  __shared__ float tile[64][65];
  const int bid = blockIdx.x;
  const int t = threadIdx.x;
  if (bid < 10240) {
    const int i = bid * 256 + t;  // 2621440 float4s total
    if (i < 2097152) {            // mem (sel=0) | x (sel=1), b-major dest
      const int off = i & 1048575;
      const int sel = i >> 20;
      const float4 v = ((const float4*)(sel ? x : mem))[off];
      const int row = off >> 8, d4 = off & 255;        // src row = t*4+b
      const int drow = (row & 3) * 2048 + sel * 1024 + (row >> 2);
      half4v h;
      h[0] = (half_t)v.x; h[1] = (half_t)v.y; h[2] = (half_t)v.z; h[3] = (half_t)v.w;
      ((half4v*)cbf)[(drow << 8) + d4] = h;
    } else {                      // pos, linear
      const int off = i - 2097152;
      const float4 v = ((const float4*)pos)[off];
      half4v h;
      h[0] = (half_t)v.x; h[1] = (half_t)v.y; h[2] = (half_t)v.z; h[3] = (half_t)v.w;
      ((half4v*)posb)[off] = h;
    }
    return;
  }
  const int tb = bid - 10240;
  const int bx = tb & 15, y = tb >> 4;
  const float* src; half_t* dst; int C, c0;
  if (y < 48)      { src = Wqkv; dst = wqkvT; C = 3072; c0 = y * 64; }
  else if (y < 64) { src = Wrel; dst = wrelT; C = 1024; c0 = (y - 48) * 64; }
  else             { src = Wo;   dst = woT;   C = 1024; c0 = (y - 64) * 64; }
  const int r0 = bx * 64;
  const int tx = t & 63, ty4 = t >> 6;
#pragma unroll
  for (int k = 0; k < 16; ++k) {
    int row = k * 4 + ty4;
    tile[row][tx] = src[(size_t)(r0 + row) * C + c0 + tx];
  }
  __syncthreads();
#pragma unroll
  for (int k = 0; k < 16; ++k) {
    int orow = k * 4 + ty4;
    dst[(size_t)(c0 + orow) * 1024 + r0 + tx] = (half_t)tile[tx][orow];
  }
}

// ------------- 256^2-tile double-buffered 2-phase GEMM: qk | vT | pos ------
#define QP_STAGE(buf_, k0_)                                                    \
  do {                                                                         \
    _Pragma("unroll") for (int i_ = 0; i_ < 4; ++i_) {                         \
      const int r0_ = wave * 32 + i_ * 8;                                      \
      async_copy16(&A[(size_t)(m0 + r0_ + srw) * 1024 + (k0_) + scl],          \
                   &ldsA[buf_][r0_][0]);                                       \
      async_copy16(&B[(size_t)(n0 + r0_ + srw) * 1024 + (k0_) + scl],          \
                   &ldsB[buf_][r0_][0]);                                       \
    }                                                                          \
  } while (0)

#define QP_COMPUTE(d_)                                                         \
  do {                                                                         \
    _Pragma("unroll") for (int ks_ = 0; ks_ < 2; ++ks_) {                      \
      half8 bf_[4];                                                            \
      _Pragma("unroll") for (int nt_ = 0; nt_ < 4; ++nt_) {                    \
        const int rw_ = wn + nt_ * 16 + l15;                                   \
        bf_[nt_] =                                                             \
            *(const half8*)&ldsB[d_][rw_][((ks_ * 4 + quad) ^ (rw_ & 7)) * 8]; \
      }                                                                        \
      half8 af_[8];                                                            \
      _Pragma("unroll") for (int mt_ = 0; mt_ < 8; ++mt_) {                    \
        const int rw_ = wm + mt_ * 16 + l15;                                   \
        af_[mt_] =                                                             \
            *(const half8*)&ldsA[d_][rw_][((ks_ * 4 + quad) ^ (rw_ & 7)) * 8]; \
      }                                                                        \
      __builtin_amdgcn_s_setprio(1);                                           \
      _Pragma("unroll") for (int mt_ = 0; mt_ < 8; ++mt_)                      \
        _Pragma("unroll") for (int nt_ = 0; nt_ < 4; ++nt_)                    \
          acc[mt_][nt_] = __builtin_amdgcn_mfma_f32_16x16x32_f16(              \
              af_[mt_], bf_[nt_], acc[mt_][nt_], 0, 0, 0);                     \
      __builtin_amdgcn_s_setprio(0);                                           \
    }                                                                          \
  } while (0)

__global__ __launch_bounds__(512, 2) void k_gemm_qkv_pos(const half_t* __restrict__ cbf,
                                                         const half_t* __restrict__ wqkvT,
                                                         half_t* __restrict__ qkv,
                                                         const half_t* __restrict__ posb,
                                                         const half_t* __restrict__ wrelT,
                                                         half_t* __restrict__ rb,
                                                         half_t* __restrict__ vT) {
  __shared__ half_t ldsA[2][256][64];   // 64 KB
  __shared__ half_t ldsB[2][256][64];   // 64 KB
  const int t = threadIdx.x;
  const int wave = t >> 6, lane = t & 63, quad = lane >> 4, l15 = lane & 15;
  const int bid0 = blockIdx.x;
  const int bid = (bid0 & 7) * 52 + (bid0 >> 3);
  const half_t* A; const half_t* B; half_t* C; int m0, n0, N;
  if (bid < 256) {        // Q,K: cbf[8192] @ Wqk^T[2048] -> qkv[8192][2048]
    A = cbf;  B = wqkvT; C = qkv; N = 2048;
    m0 = (bid & 31) * 256; n0 = (bid >> 5) * 256;
  } else if (bid < 384) { // V^T: Wv^T[1024] @ cbf^T -> vT[1024][8192]
    const int b2 = bid - 256;
    A = wqkvT + 2048 * 1024; B = cbf; C = vT; N = 8192;
    m0 = (b2 & 3) * 256; n0 = (b2 >> 2) * 256;
  } else {                // pos: posb[2048] @ Wrel^T -> rb[2048][1024]
    const int b2 = bid - 384;
    A = posb; B = wrelT; C = rb; N = 1024;
    m0 = (b2 & 7) * 256; n0 = (b2 >> 3) * 256;
  }
  const int srw = lane >> 3;
  const int scl = ((lane & 7) ^ srw) * 8;
  const int wm = (wave >> 2) * 128, wn = (wave & 3) * 64;

  f32x4 acc[8][4] = {};

  QP_STAGE(0, 0);
  __syncthreads();
  int d = 0;
  for (int kt = 0; kt < 15; ++kt) {
    QP_STAGE(d ^ 1, (kt + 1) * 64);
    QP_COMPUTE(d);
    __syncthreads();
    d ^= 1;
  }
  QP_COMPUTE(d);

#pragma unroll
  for (int mt = 0; mt < 8; ++mt)
#pragma unroll
    for (int nt = 0; nt < 4; ++nt)
#pragma unroll
      for (int r = 0; r < 4; ++r)
        C[(size_t)(m0 + wm + mt * 16 + quad * 4 + r) * N + n0 + wn + nt * 16 + l15] =
            (half_t)acc[mt][nt][r];
}

// ------- proj GEMM: 128x256 tiles, 8-wave dbuf 2-phase, split-K=2 ----------
#define PJ_STAGE(buf_, k0_)                                                    \
  do {                                                                         \
    _Pragma("unroll") for (int i_ = 0; i_ < 2; ++i_) {                         \
      const int r0_ = wave * 16 + i_ * 8;                                      \
      async_copy16(&A[(size_t)(m0 + r0_ + srw) * 1024 + (k0_) + scl],          \
                   &pA[buf_][r0_][0]);                                         \
    }                                                                          \
    _Pragma("unroll") for (int i_ = 0; i_ < 4; ++i_) {                         \
      const int r0_ = wave * 32 + i_ * 8;                                      \
      async_copy16(&B[(size_t)(n0 + r0_ + srw) * 1024 + (k0_) + scl],          \
                   &pB[buf_][r0_][0]);                                         \
    }                                                                          \
  } while (0)

#define PJ_COMPUTE(d_)                                                         \
  do {                                                                         \
    _Pragma("unroll") for (int ks_ = 0; ks_ < 2; ++ks_) {                      \
      half8 bf_[4];                                                            \
      _Pragma("unroll") for (int nt_ = 0; nt_ < 4; ++nt_) {                    \
        const int rw_ = wn + nt_ * 16 + l15;                                   \
        bf_[nt_] =                                                             \
            *(const half8*)&pB[d_][rw_][((ks_ * 4 + quad) ^ (rw_ & 7)) * 8];   \
      }                                                                        \
      half8 af_[4];                                                            \
      _Pragma("unroll") for (int mt_ = 0; mt_ < 4; ++mt_) {                    \
        const int rw_ = wm + mt_ * 16 + l15;                                   \
        af_[mt_] =                                                             \
            *(const half8*)&pA[d_][rw_][((ks_ * 4 + quad) ^ (rw_ & 7)) * 8];   \
      }                                                                        \
      __builtin_amdgcn_s_setprio(1);                                           \
      _Pragma("unroll") for (int mt_ = 0; mt_ < 4; ++mt_)                      \
        _Pragma("unroll") for (int nt_ = 0; nt_ < 4; ++nt_)                    \
          acc[mt_][nt_] = __builtin_amdgcn_mfma_f32_16x16x32_f16(              \
              af_[mt_], bf_[nt_], acc[mt_][nt_], 0, 0, 0);                     \
      __builtin_amdgcn_s_setprio(0);                                           \
    }                                                                          \
  } while (0)

__global__ __launch_bounds__(512, 2) void k_gemm_proj(const half_t* __restrict__ av,
                                                      const half_t* __restrict__ woT,
                                                      half_t* __restrict__ out0,
                                                      half_t* __restrict__ out1) {
  __shared__ half_t pA[2][128][64];     // 32 KB
  __shared__ half_t pB[2][256][64];     // 64 KB
  const int t = threadIdx.x;
  const int wave = t >> 6, lane = t & 63, quad = lane >> 4, l15 = lane & 15;
  const int bid0 = blockIdx.x;
  const int bs = (bid0 & 7) * 32 + (bid0 >> 3);
  const int h = bs >> 7, b2 = bs & 127;
  const int m0 = (b2 & 31) * 128, n0 = (b2 >> 5) * 256;
  const half_t* A = av + h * 512;
  const half_t* B = woT + h * 512;
  half_t* C = h ? out1 : out0;
  const int srw = lane >> 3;
  const int scl = ((lane & 7) ^ srw) * 8;
  const int wm = (wave >> 2) * 64, wn = (wave & 3) * 64;

  f32x4 acc[4][4] = {};

  PJ_STAGE(0, 0);
  __syncthreads();
  int d = 0;
  for (int kt = 0; kt < 7; ++kt) {      // K=512 -> 8 K-tiles
    PJ_STAGE(d ^ 1, (kt + 1) * 64);
    PJ_COMPUTE(d);
    __syncthreads();
    d ^= 1;
  }
  PJ_COMPUTE(d);

#pragma unroll
  for (int mt = 0; mt < 4; ++mt)
#pragma unroll
    for (int nt = 0; nt < 4; ++nt)
#pragma unroll
      for (int r = 0; r < 4; ++r)
        C[(size_t)(m0 + wm + mt * 16 + quad * 4 + r) * 1024 + n0 + wn + nt * 16 + l15] =
            (half_t)acc[mt][nt][r];
}

// ---------------- flash attention with Transformer-XL relative shift --------
// R16: 256 threads = 4 waves; each wave owns 32 q-rows as two 16-row groups
// g = wave*2 + hi (g in 0..7: geometry identical to R8's 8-wave version).
// K/V fragment reads shared across hi (1 read -> 2 MFMAs); E-window union
// (6 tiles) serves both groups' 5-tile windows. Ring/barrier/mask logic
// byte-identical per group.
__global__ __launch_bounds__(256, 2) void k_attn(const half_t* __restrict__ qkv,
                                                 const half_t* __restrict__ rbuf,
                                                 const half_t* __restrict__ vT,
                                                 const float* __restrict__ pbu,
                                                 const float* __restrict__ pbv,
                                                 half_t* __restrict__ av) {
  __shared__ __align__(16) half_t ldsK[64][64];        // [key][dh], XOR chunks
  __shared__ __align__(16) half_t ldsV[64][64];        // [dh][key], XOR chunks
  __shared__ __align__(16) half_t ldsR[256][64];       // r ring, XOR chunks
  __shared__ __align__(16) half_t ldsP[4][2][16][72];  // per-wave/hi P
  const int t = threadIdx.x;
  const int wave = t >> 6, lane = t & 63, quad = lane >> 4, l15 = lane & 15;

  // work-pairing swizzle: CU-co-resident blocks get x and 7-x
  const int li = blockIdx.x + 8 * blockIdx.y;
  const int c = li & 255, kr = li >> 8;
  const int xe = kr == 0 ? (c & 7) : 7 - (c & 7);
  const int bn = (c >> 3) + (kr << 5);
  const int i0 = xe * 128;
  const int b = bn >> 4, n = bn & 15;
  const int p0 = 896 - i0;  // global r-row of ring origin at tile 0

  // q fragments per hi with biases folded in (group g = wave*2+hi)
  half8 qu[2][2], qv[2][2];
#pragma unroll
  for (int hi = 0; hi < 2; ++hi)
#pragma unroll
    for (int ks = 0; ks < 2; ++ks) {
      const int dh0 = ks * 32 + quad * 8;
      const int ig = i0 + (wave * 2 + hi) * 16 + l15;
      const half8 qf = *(const half8*)&qkv[((size_t)(b * 2048 + M_LEN + ig)) * 2048 + n * 64 + dh0];
#pragma unroll
      for (int j = 0; j < 8; ++j) {
        const float qj = (float)qf[j];
        qu[hi][ks][j] = (half_t)(qj + pbu[n * 64 + dh0 + j]);
        qv[hi][ks][j] = (half_t)(qj + pbv[n * 64 + dh0 + j]);
      }
    }

  // E-shift lane rotation constants (lane-only; same for both hi groups)
  int bperm_idx[4];
  bool lo_sel[4];
#pragma unroll
  for (int r = 0; r < 4; ++r) {
    const int irow = quad * 4 + r;
    bperm_idx[r] = ((lane & 48) | ((l15 + 15 - irow) & 15)) << 2;
    lo_sel[r] = (l15 <= irow);
  }

  f32x4 oacc[2][4] = {};
  float lpart[2][4] = {};
  const float k1 = 0.125f * 1.44269504088896f;  // scale * log2(e)
  const float kC = -4.0f * 1.44269504088896f;   // -C * log2(e)

  // staging geometry: 256 thr cover 32 rows x 8 chunks per pass (2 passes)
  const int sr = t >> 3, sc3 = t & 7;
  const int sxk = (sc3 ^ (sr & 7)) * 8;  // (sr+32)&7 == sr&7 -> same chunk

  const int ntile = xe * 2 + 18;

  // ---- prologue: ring rows [p0, p0+255] written directly (pre-barrier) ----
#pragma unroll
  for (int i = 0; i < 8; ++i) {
    const int rr = i * 32 + sr;
    const int pg = p0 + rr;
    const int ps = pg > 2047 ? 2047 : pg;
    const half8 rv = *(const half8*)&rbuf[(size_t)ps * 1024 + n * 64 + sc3 * 8];
    *(half8*)&ldsR[pg & 255][(sc3 ^ (pg & 7)) * 8] = rv;
  }
  // K/V tile 0 prefetch (2 rows/thread)
  half8 kreg0 = *(const half8*)&qkv[((size_t)(b * 2048 + sr)) * 2048 + 1024 + n * 64 + sc3 * 8];
  half8 kreg1 = *(const half8*)&qkv[((size_t)(b * 2048 + sr + 32)) * 2048 + 1024 + n * 64 + sc3 * 8];
  half8 vreg0 = *(const half8*)&vT[((size_t)(n * 64 + sr)) * 8192 + b * 2048 + sc3 * 8];
  half8 vreg1 = *(const half8*)&vT[((size_t)(n * 64 + sr + 32)) * 8192 + b * 2048 + sc3 * 8];
  half8 rpre0, rpre1;

  for (int kt = 0; kt < ntile; ++kt) {
    const int j0 = kt * 64;

    __syncthreads();  // prev-iter LDS reads done
    *(half8*)&ldsK[sr][sxk] = kreg0;
    *(half8*)&ldsK[sr + 32][sxk] = kreg1;
    *(half8*)&ldsV[sr][sxk] = vreg0;
    *(half8*)&ldsV[sr + 32][sxk] = vreg1;
    if (kt > 0) {
      const int pw0 = j0 + p0 + 192 + sr;
      *(half8*)&ldsR[pw0 & 255][(sc3 ^ (pw0 & 7)) * 8] = rpre0;
      const int pw1 = pw0 + 32;
      *(half8*)&ldsR[pw1 & 255][(sc3 ^ (pw1 & 7)) * 8] = rpre1;
    }
    __syncthreads();

    // ---- prefetch tile kt+1 ----
    if (kt + 1 < ntile) {
      const int j0n = j0 + 64;
      kreg0 = *(const half8*)&qkv[((size_t)(b * 2048 + j0n + sr)) * 2048 + 1024 + n * 64 + sc3 * 8];
      kreg1 = *(const half8*)&qkv[((size_t)(b * 2048 + j0n + sr + 32)) * 2048 + 1024 + n * 64 + sc3 * 8];
      vreg0 = *(const half8*)&vT[((size_t)(n * 64 + sr)) * 8192 + b * 2048 + j0n + sc3 * 8];
      vreg1 = *(const half8*)&vT[((size_t)(n * 64 + sr + 32)) * 8192 + b * 2048 + j0n + sc3 * 8];
      const int pn0 = j0 + p0 + 256 + sr;
      const int pc0 = pn0 > 2047 ? 2047 : pn0;
      rpre0 = *(const half8*)&rbuf[(size_t)pc0 * 1024 + n * 64 + sc3 * 8];
      const int pn1 = pn0 + 32;
      const int pc1 = pn1 > 2047 ? 2047 : pn1;
      rpre1 = *(const half8*)&rbuf[(size_t)pc1 * 1024 + n * 64 + sc3 * 8];
    }

    // ---- AC = (q+u) @ K^T : K-fragment read shared across hi ----
    f32x4 ac[2][4] = {};
    f32x4 ea[2][5] = {};
    __builtin_amdgcn_s_setprio(1);
#pragma unroll
    for (int ks = 0; ks < 2; ++ks)
#pragma unroll
      for (int nt = 0; nt < 4; ++nt) {
        const int row = nt * 16 + l15;
        const half8 kf = *(const half8*)&ldsK[row][((ks * 4 + quad) ^ (row & 7)) * 8];
        ac[0][nt] = __builtin_amdgcn_mfma_f32_16x16x32_f16(qu[0][ks], kf, ac[0][nt], 0, 0, 0);
        ac[1][nt] = __builtin_amdgcn_mfma_f32_16x16x32_f16(qu[1][ks], kf, ac[1][nt], 0, 0, 0);
      }

    // ---- E windows: union of both groups' windows = 6 tiles of 16 ----
    // group g=wave*2+hi window start = j0+p0+112-g*16; union starts at hi=1.
    const int rbgU = j0 + p0 + 112 - (wave * 2 + 1) * 16;
#pragma unroll
    for (int ks = 0; ks < 2; ++ks) {
      half8 rf[6];
#pragma unroll
      for (int u = 0; u < 6; ++u) {
        const int pr = rbgU + u * 16 + l15;
        rf[u] = *(const half8*)&ldsR[pr & 255][((ks * 4 + quad) ^ (pr & 7)) * 8];
      }
#pragma unroll
      for (int et = 0; et < 5; ++et) {
        ea[0][et] = __builtin_amdgcn_mfma_f32_16x16x32_f16(qv[0][ks], rf[et + 1], ea[0][et], 0, 0, 0);
        ea[1][et] = __builtin_amdgcn_mfma_f32_16x16x32_f16(qv[1][ks], rf[et], ea[1][et], 0, 0, 0);
      }
    }
    __builtin_amdgcn_s_setprio(0);

    // ---- scores -> p per hi; E shift via in-register bpermute ----
#pragma unroll
    for (int hi = 0; hi < 2; ++hi) {
      const int ibg = i0 + (wave * 2 + hi) * 16;
      const bool maskt = j0 > ibg + 960;
#pragma unroll
      for (int r = 0; r < 4; ++r) {
        const int irow = quad * 4 + r;
        const int ig = ibg + irow;
        float rot[5];
#pragma unroll
        for (int et = 0; et < 5; ++et)
          rot[et] = __int_as_float(
              __builtin_amdgcn_ds_bpermute(bperm_idx[r], __float_as_int(ea[hi][et][r])));
        float psum = 0.f;
#pragma unroll
        for (int nt = 0; nt < 4; ++nt) {
          const float ev = lo_sel[r] ? rot[nt] : rot[nt + 1];
          const int cj = nt * 16 + l15;
          float p = __builtin_amdgcn_exp2f(fmaf(ac[hi][nt][r] + ev, k1, kC));
          if (maskt && (j0 + cj > ig + M_LEN)) p = 0.f;
          psum += p;
          ldsP[wave][hi][irow][cj] = (half_t)p;
        }
        lpart[hi][r] += psum;
      }
    }
    __builtin_amdgcn_wave_barrier();  // P round trip is wave-internal

    // ---- PV: V-fragment read shared across hi ----
    half8 pa0[2], pa1[2];
#pragma unroll
    for (int ks = 0; ks < 2; ++ks) {
      pa0[ks] = *(const half8*)&ldsP[wave][0][l15][ks * 32 + quad * 8];
      pa1[ks] = *(const half8*)&ldsP[wave][1][l15][ks * 32 + quad * 8];
    }
    __builtin_amdgcn_s_setprio(1);
#pragma unroll
    for (int ks = 0; ks < 2; ++ks)
#pragma unroll
      for (int dnt = 0; dnt < 4; ++dnt) {
        const int row = dnt * 16 + l15;
        const half8 vf = *(const half8*)&ldsV[row][((ks * 4 + quad) ^ (row & 7)) * 8];
        oacc[0][dnt] = __builtin_amdgcn_mfma_f32_16x16x32_f16(pa0[ks], vf, oacc[0][dnt], 0, 0, 0);
        oacc[1][dnt] = __builtin_amdgcn_mfma_f32_16x16x32_f16(pa1[ks], vf, oacc[1][dnt], 0, 0, 0);
      }
    __builtin_amdgcn_s_setprio(0);
  }

  // final l-sum reduction + normalize + store (per hi group)
#pragma unroll
  for (int hi = 0; hi < 2; ++hi)
#pragma unroll
    for (int r = 0; r < 4; ++r) {
      float l = lpart[hi][r];
#pragma unroll
      for (int off = 1; off < 16; off <<= 1) l += __shfl_xor(l, off);
      const float inv = 1.0f / l;
      const int ig = i0 + (wave * 2 + hi) * 16 + quad * 4 + r;
#pragma unroll
      for (int dnt = 0; dnt < 4; ++dnt)
        av[((size_t)ig * BATCH + b) * 1024 + n * 64 + dnt * 16 + l15] = (half_t)(oacc[hi][dnt][r] * inv);
    }
}

// -------- residual + LayerNorm (one block per row; sums 2 fp16 partials) ----
__global__ __launch_bounds__(256) void k_ln(const float* __restrict__ x,
                                            const half_t* __restrict__ ao0,
                                            const half_t* __restrict__ ao1,
                                            const float* __restrict__ gamma,
                                            const float* __restrict__ beta,
                                            float* __restrict__ out) {
  const int row = blockIdx.x;
  const int t = threadIdx.x;
  const float4 xv = ((const float4*)(x + (size_t)row * 1024))[t];
  const half4v a4 = ((const half4v*)(ao0 + (size_t)row * 1024))[t];
  const half4v b4 = ((const half4v*)(ao1 + (size_t)row * 1024))[t];
  const float y0 = xv.x + (float)a4[0] + (float)b4[0];
  const float y1 = xv.y + (float)a4[1] + (float)b4[1];
  const float y2 = xv.z + (float)a4[2] + (float)b4[2];
  const float y3 = xv.w + (float)a4[3] + (float)b4[3];
  float s = y0 + y1 + y2 + y3;
  float ss = y0 * y0 + y1 * y1 + y2 * y2 + y3 * y3;
#pragma unroll
  for (int off = 1; off < 64; off <<= 1) {
    s += __shfl_xor(s, off);
    ss += __shfl_xor(ss, off);
  }
  __shared__ float sb[4], ssb[4];
  if ((t & 63) == 0) { sb[t >> 6] = s; ssb[t >> 6] = ss; }
  __syncthreads();
  s = sb[0] + sb[1] + sb[2] + sb[3];
  ss = ssb[0] + ssb[1] + ssb[2] + ssb[3];
  const float mean = s * (1.f / 1024.f);
  const float var = ss * (1.f / 1024.f) - mean * mean;
  const float rstd = rsqrtf(var + 1e-5f);
  const float4 g = ((const float4*)gamma)[t];
  const float4 be = ((const float4*)beta)[t];
  float4 o;
  o.x = (y0 - mean) * rstd * g.x + be.x;
  o.y = (y1 - mean) * rstd * g.y + be.y;
  o.z = (y2 - mean) * rstd * g.z + be.z;
  o.w = (y3 - mean) * rstd * g.w + be.w;
  ((float4*)(out + (size_t)row * 1024))[t] = o;
}

// ---------------------------------------------------------------------------
extern "C" void kernel_launch(void* const* d_in, const int* in_sizes, int n_in,
                              void* d_out, int out_size, void* d_ws, size_t ws_size,
                              hipStream_t stream) {
  const float* x     = (const float*)d_in[0];
  const float* pos   = (const float*)d_in[1];
  const float* pbu   = (const float*)d_in[2];
  const float* pbv   = (const float*)d_in[3];
  const float* mem   = (const float*)d_in[4];
  const float* Wqkv  = (const float*)d_in[5];
  const float* Wrel  = (const float*)d_in[6];
  const float* Wo    = (const float*)d_in[7];
  const float* gamma = (const float*)d_in[8];
  const float* beta  = (const float*)d_in[9];
  float* out = (float*)d_out;

  half_t* ws    = (half_t*)d_ws;
  half_t* cbf   = ws;                 // [4][2048][1024] b-major
  half_t* posb  = cbf + 8388608;      // [2048][1024]
  half_t* wqkvT = posb + 2097152;     // [3072][1024]
  half_t* wrelT = wqkvT + 3145728;    // [1024][1024]
  half_t* woT   = wrelT + 1048576;    // [1024][1024]
  half_t* qkv   = woT + 1048576;      // [4][2048][2048] b-major (Q|K)
  half_t* rb    = qkv + 16777216;     // [2048][1024]
  half_t* vT    = rb + 2097152;       // [1024][4*2048]
  half_t* av    = vT + 8388608;       // [4096][1024]
  half_t* aout0 = qkv;                // reuse qkv region (partial 0)
  half_t* aout1 = qkv + 4194304;      // partial 1

  k_pre<<<11520, 256, 0, stream>>>(mem, x, pos, Wqkv, Wrel, Wo, cbf, posb, wqkvT, wrelT, woT);
  k_gemm_qkv_pos<<<416, 512, 0, stream>>>(cbf, wqkvT, qkv, posb, wrelT, rb, vT);
  k_attn<<<dim3(8, 64), 256, 0, stream>>>(qkv, rb, vT, pbu, pbv, av);
  k_gemm_proj<<<256, 512, 0, stream>>>(av, woT, aout0, aout1);
  k_ln<<<4096, 256, 0, stream>>>(x, aout0, aout1, gamma, beta, out);
}

// Round 10
// 309.139 us; speedup vs baseline: 1.0517x; 1.0517x over previous
//
#include <hip/hip_runtime.h>
#include <math.h>
#include <cstdint>
#include <cstddef>

// ---------------------------------------------------------------------------
// Transformer-XL relative multihead attention, MI355X (gfx950)
// S=1024, M=1024, T=2048, B=4, D=1024, H=16, DH=64
// R18: (a) k_attn reverted to R15's proven R8-structure (92.0us; R17's
//      4-wave read-sharing cost +21% -> attn is latency/TLP-bound, closed).
//      (b) qkv GEMM rebuilt as 8-phase counted-vmcnt schedule (T3+T4):
//      per K-tile 4 phases = 4 C-quadrants x 16 MFMA; per phase stage one
//      half-tile (2 copies/thread) of a future tile into a region whose last
//      reader finished >=1 barrier earlier (A1@ph1,B0@ph2,B1@ph3,A0'@ph4);
//      one vmcnt(2)+barrier gate per K-tile (1 half-tile in flight across
//      the gate; never vmcnt(0) in loop). Raw s_barrier (no drain);
//      ds_read->MFMA deps compiler-tracked; MFMA accumulate order identical
//      to R15 -> bitwise-same C. setprio around MFMA quadrants (T5).
// ---------------------------------------------------------------------------

typedef _Float16 half_t;
typedef _Float16 half8 __attribute__((ext_vector_type(8)));
typedef _Float16 half4v __attribute__((ext_vector_type(4)));
typedef float f32x4 __attribute__((ext_vector_type(4)));

#define S_LEN 1024
#define M_LEN 1024
#define T_LEN 2048
#define BATCH 4
#define NHEAD 16

__device__ inline void async_copy16(const half_t* g, half_t* l) {
  __builtin_amdgcn_global_load_lds(
      (const __attribute__((address_space(1))) void*)g,
      (__attribute__((address_space(3))) void*)l, 16, 0, 0);
}

// ---- fused pre-pass: convert (b-major cbf | posb) + weight transposes -----
__global__ __launch_bounds__(256) void k_pre(const float* __restrict__ mem,
                                             const float* __restrict__ x,
                                             const float* __restrict__ pos,
                                             const float* __restrict__ Wqkv,
                                             const float* __restrict__ Wrel,
                                             const float* __restrict__ Wo,
                                             half_t* __restrict__ cbf,
                                             half_t* __restrict__ posb,
                                             half_t* __restrict__ wqkvT,
                                             half_t* __restrict__ wrelT,
                                             half_t* __restrict__ woT) {
  __shared__ float tile[64][65];
  const int bid = blockIdx.x;
  const int t = threadIdx.x;
  if (bid < 10240) {
    const int i = bid * 256 + t;  // 2621440 float4s total
    if (i < 2097152) {            // mem (sel=0) | x (sel=1), b-major dest
      const int off = i & 1048575;
      const int sel = i >> 20;
      const float4 v = ((const float4*)(sel ? x : mem))[off];
      const int row = off >> 8, d4 = off & 255;        // src row = t*4+b
      const int drow = (row & 3) * 2048 + sel * 1024 + (row >> 2);
      half4v h;
      h[0] = (half_t)v.x; h[1] = (half_t)v.y; h[2] = (half_t)v.z; h[3] = (half_t)v.w;
      ((half4v*)cbf)[(drow << 8) + d4] = h;
    } else {                      // pos, linear
      const int off = i - 2097152;
      const float4 v = ((const float4*)pos)[off];
      half4v h;
      h[0] = (half_t)v.x; h[1] = (half_t)v.y; h[2] = (half_t)v.z; h[3] = (half_t)v.w;
      ((half4v*)posb)[off] = h;
    }
    return;
  }
  const int tb = bid - 10240;
  const int bx = tb & 15, y = tb >> 4;
  const float* src; half_t* dst; int C, c0;
  if (y < 48)      { src = Wqkv; dst = wqkvT; C = 3072; c0 = y * 64; }
  else if (y < 64) { src = Wrel; dst = wrelT; C = 1024; c0 = (y - 48) * 64; }
  else             { src = Wo;   dst = woT;   C = 1024; c0 = (y - 64) * 64; }
  const int r0 = bx * 64;
  const int tx = t & 63, ty4 = t >> 6;
#pragma unroll
  for (int k = 0; k < 16; ++k) {
    int row = k * 4 + ty4;
    tile[row][tx] = src[(size_t)(r0 + row) * C + c0 + tx];
  }
  __syncthreads();
#pragma unroll
  for (int k = 0; k < 16; ++k) {
    int orow = k * 4 + ty4;
    dst[(size_t)(c0 + orow) * 1024 + r0 + tx] = (half_t)tile[tx][orow];
  }
}

// ---------- 256^2-tile 8-phase counted-vmcnt GEMM: qk | vT | pos -----------
// 512 threads = 8 waves (2M x 4N); per-wave C = 128x64 (8x4 fragments).
// LDS: sA/sB [dbuf][half:128rows][128][64] halves; buffer = kt&1.
// Phase p of K-tile kt: {ds-load reg subtile; stage 1 half-tile; barrier;
// setprio(1); 16 MFMA (quadrant); setprio(0); barrier}. Gate per K-tile:
// s_waitcnt vmcnt(2) + barrier (one half-tile = 2 copies/thread in flight).
// Stage targets' last readers (barrier-separated, race-checked):
//  ph1: (kt+1).A1 over (kt-1).A1 [last read (kt-1).ph3]
//  ph2: (kt+1).B0 over (kt-1).B0 [last read (kt-1).ph2]
//  ph3: (kt+1).B1 over (kt-1).B1 [last read (kt-1).ph2]
//  ph4: (kt+2).A0 over (kt).A0   [last read (kt).ph3]
// Tail tiles 16/17 staged unguarded (sources stay inside ws; keeps vmcnt
// arithmetic uniform; nothing reads them).
#define QK_STA(tile_, h_)                                                      \
  do {                                                                         \
    _Pragma("unroll") for (int i_ = 0; i_ < 2; ++i_) {                         \
      const int r_ = (t >> 3) + i_ * 64;                                       \
      async_copy16(&A[(size_t)(m0 + (h_) * 128 + r_) * 1024 +                  \
                      (tile_) * 64 + scl],                                     \
                   &sA[(tile_) & 1][h_][r_][(t & 7) * 8]);                     \
    }                                                                          \
  } while (0)

#define QK_STB(tile_, h_)                                                      \
  do {                                                                         \
    _Pragma("unroll") for (int i_ = 0; i_ < 2; ++i_) {                         \
      const int r_ = (t >> 3) + i_ * 64;                                       \
      async_copy16(&B[(size_t)(n0 + (h_) * 128 + r_) * 1024 +                  \
                      (tile_) * 64 + scl],                                     \
                   &sB[(tile_) & 1][h_][r_][(t & 7) * 8]);                     \
    }                                                                          \
  } while (0)

#define QK_LDA(d_, mq_)                                                        \
  do {                                                                         \
    _Pragma("unroll") for (int mt_ = 0; mt_ < 4; ++mt_)                        \
      _Pragma("unroll") for (int ks_ = 0; ks_ < 2; ++ks_) {                    \
        const int lr_ = ((mq_) * 4 + mt_) * 16 + l15;                          \
        af[mt_][ks_] = *(const half8*)&sA[d_][wha][lr_]                        \
                           [((ks_ * 4 + quad) ^ (lr_ & 7)) * 8];               \
      }                                                                        \
  } while (0)

#define QK_LDB(d_, nh_)                                                        \
  do {                                                                         \
    _Pragma("unroll") for (int ntl_ = 0; ntl_ < 2; ++ntl_)                     \
      _Pragma("unroll") for (int ks_ = 0; ks_ < 2; ++ks_) {                    \
        const int lr_ = wnl + ((nh_) * 2 + ntl_) * 16 + l15;                   \
        bf[nh_][ntl_][ks_] = *(const half8*)&sB[d_][whb][lr_]                  \
                                 [((ks_ * 4 + quad) ^ (lr_ & 7)) * 8];         \
      }                                                                        \
  } while (0)

#define QK_MMA(mq_, nh_)                                                       \
  do {                                                                         \
    __builtin_amdgcn_s_setprio(1);                                             \
    _Pragma("unroll") for (int mt_ = 0; mt_ < 4; ++mt_)                        \
      _Pragma("unroll") for (int ntl_ = 0; ntl_ < 2; ++ntl_)                   \
        _Pragma("unroll") for (int ks_ = 0; ks_ < 2; ++ks_)                    \
          acc[(mq_) * 4 + mt_][(nh_) * 2 + ntl_] =                             \
              __builtin_amdgcn_mfma_f32_16x16x32_f16(                          \
                  af[mt_][ks_], bf[nh_][ntl_][ks_],                            \
                  acc[(mq_) * 4 + mt_][(nh_) * 2 + ntl_], 0, 0, 0);            \
    __builtin_amdgcn_s_setprio(0);                                             \
  } while (0)

__global__ __launch_bounds__(512, 2) void k_gemm_qkv_pos(const half_t* __restrict__ cbf,
                                                         const half_t* __restrict__ wqkvT,
                                                         half_t* __restrict__ qkv,
                                                         const half_t* __restrict__ posb,
                                                         const half_t* __restrict__ wrelT,
                                                         half_t* __restrict__ rb,
                                                         half_t* __restrict__ vT) {
  __shared__ half_t sA[2][2][128][64];   // 64 KB
  __shared__ half_t sB[2][2][128][64];   // 64 KB
  const int t = threadIdx.x;
  const int wave = t >> 6, lane = t & 63, quad = lane >> 4, l15 = lane & 15;
  // bijective XCD swizzle (416 % 8 == 0): each XCD gets a contiguous chunk
  const int bid0 = blockIdx.x;
  const int bid = (bid0 & 7) * 52 + (bid0 >> 3);
  const half_t* A; const half_t* B; half_t* C; int m0, n0, N;
  if (bid < 256) {        // Q,K: cbf[8192] @ Wqk^T[2048] -> qkv[8192][2048]
    A = cbf;  B = wqkvT; C = qkv; N = 2048;
    m0 = (bid & 31) * 256; n0 = (bid >> 5) * 256;
  } else if (bid < 384) { // V^T: Wv^T[1024] @ cbf^T -> vT[1024][8192]
    const int b2 = bid - 256;
    A = wqkvT + 2048 * 1024; B = cbf; C = vT; N = 8192;
    m0 = (b2 & 3) * 256; n0 = (b2 >> 2) * 256;
  } else {                // pos: posb[2048] @ Wrel^T -> rb[2048][1024]
    const int b2 = bid - 384;
    A = posb; B = wrelT; C = rb; N = 1024;
    m0 = (b2 & 7) * 256; n0 = (b2 >> 3) * 256;
  }
  // staging geometry: 512 threads cover 64 rows x 8 chunks per copy round;
  // XOR pre-swizzled global source chunk, linear LDS dest (rule #21).
  const int scl = ((t & 7) ^ ((t >> 3) & 7)) * 8;
  // fragment geometry
  const int wm = (wave >> 2) * 128, wn = (wave & 3) * 64;
  const int wha = wave >> 2;            // wave's static A-half
  const int whb = (wave & 3) >> 1;      // wave's static B-half
  const int wnl = (wave & 1) * 64;      // local B row base within half

  f32x4 acc[8][4] = {};
  half8 af[4][2], bf[2][2][2];

  // prologue: tile 0 fully + (1).A0 -> exactly 1 half-tile in flight at gate
  QK_STA(0, 0); QK_STA(0, 1); QK_STB(0, 0); QK_STB(0, 1); QK_STA(1, 0);

  for (int kt = 0; kt < 16; ++kt) {
    const int d = kt & 1;
    asm volatile("s_waitcnt vmcnt(2)" ::: "memory");   // counted gate, not 0
    __builtin_amdgcn_s_barrier();
    // ph1: quadrant (m0..3, n0..1)
    QK_LDA(d, 0); QK_LDB(d, 0); QK_STA(kt + 1, 1);
    __builtin_amdgcn_s_barrier();
    QK_MMA(0, 0);
    __builtin_amdgcn_s_barrier();
    // ph2: quadrant (m0..3, n2..3)
    QK_LDB(d, 1); QK_STB(kt + 1, 0);
    __builtin_amdgcn_s_barrier();
    QK_MMA(0, 1);
    __builtin_amdgcn_s_barrier();
    // ph3: quadrant (m4..7, n0..1)
    QK_LDA(d, 1); QK_STB(kt + 1, 1);
    __builtin_amdgcn_s_barrier();
    QK_MMA(1, 0);
    __builtin_amdgcn_s_barrier();
    // ph4: quadrant (m4..7, n2..3)
    QK_STA(kt + 2, 0);
    __builtin_amdgcn_s_barrier();
    QK_MMA(1, 1);
    // next iteration's gate barrier closes this tile
  }

#pragma unroll
  for (int mt = 0; mt < 8; ++mt)
#pragma unroll
    for (int nt = 0; nt < 4; ++nt)
#pragma unroll
      for (int r = 0; r < 4; ++r)
        C[(size_t)(m0 + wm + mt * 16 + quad * 4 + r) * N + n0 + wn + nt * 16 + l15] =
            (half_t)acc[mt][nt][r];
}

// ------- proj GEMM: 128x256 tiles, 8-wave dbuf 2-phase, split-K=2 ----------
#define PJ_STAGE(buf_, k0_)                                                    \
  do {                                                                         \
    _Pragma("unroll") for (int i_ = 0; i_ < 2; ++i_) {                         \
      const int r0_ = wave * 16 + i_ * 8;                                      \
      async_copy16(&A[(size_t)(m0 + r0_ + srw) * 1024 + (k0_) + scl],          \
                   &pA[buf_][r0_][0]);                                         \
    }                                                                          \
    _Pragma("unroll") for (int i_ = 0; i_ < 4; ++i_) {                         \
      const int r0_ = wave * 32 + i_ * 8;                                      \
      async_copy16(&B[(size_t)(n0 + r0_ + srw) * 1024 + (k0_) + scl],          \
                   &pB[buf_][r0_][0]);                                         \
    }                                                                          \
  } while (0)

#define PJ_COMPUTE(d_)                                                         \
  do {                                                                         \
    _Pragma("unroll") for (int ks_ = 0; ks_ < 2; ++ks_) {                      \
      half8 bf_[4];                                                            \
      _Pragma("unroll") for (int nt_ = 0; nt_ < 4; ++nt_) {                    \
        const int rw_ = wn + nt_ * 16 + l15;                                   \
        bf_[nt_] =                                                             \
            *(const half8*)&pB[d_][rw_][((ks_ * 4 + quad) ^ (rw_ & 7)) * 8];   \
      }                                                                        \
      half8 af_[4];                                                            \
      _Pragma("unroll") for (int mt_ = 0; mt_ < 4; ++mt_) {                    \
        const int rw_ = wm + mt_ * 16 + l15;                                   \
        af_[mt_] =                                                             \
            *(const half8*)&pA[d_][rw_][((ks_ * 4 + quad) ^ (rw_ & 7)) * 8];   \
      }                                                                        \
      __builtin_amdgcn_s_setprio(1);                                           \
      _Pragma("unroll") for (int mt_ = 0; mt_ < 4; ++mt_)                      \
        _Pragma("unroll") for (int nt_ = 0; nt_ < 4; ++nt_)                    \
          acc[mt_][nt_] = __builtin_amdgcn_mfma_f32_16x16x32_f16(              \
              af_[mt_], bf_[nt_], acc[mt_][nt_], 0, 0, 0);                     \
      __builtin_amdgcn_s_setprio(0);                                           \
    }                                                                          \
  } while (0)

__global__ __launch_bounds__(512, 2) void k_gemm_proj(const half_t* __restrict__ av,
                                                      const half_t* __restrict__ woT,
                                                      half_t* __restrict__ out0,
                                                      half_t* __restrict__ out1) {
  __shared__ half_t pA[2][128][64];     // 32 KB
  __shared__ half_t pB[2][256][64];     // 64 KB
  const int t = threadIdx.x;
  const int wave = t >> 6, lane = t & 63, quad = lane >> 4, l15 = lane & 15;
  const int bid0 = blockIdx.x;
  const int bs = (bid0 & 7) * 32 + (bid0 >> 3);
  const int h = bs >> 7, b2 = bs & 127;
  const int m0 = (b2 & 31) * 128, n0 = (b2 >> 5) * 256;
  const half_t* A = av + h * 512;
  const half_t* B = woT + h * 512;
  half_t* C = h ? out1 : out0;
  const int srw = lane >> 3;
  const int scl = ((lane & 7) ^ srw) * 8;
  const int wm = (wave >> 2) * 64, wn = (wave & 3) * 64;

  f32x4 acc[4][4] = {};

  PJ_STAGE(0, 0);
  __syncthreads();
  int d = 0;
  for (int kt = 0; kt < 7; ++kt) {      // K=512 -> 8 K-tiles
    PJ_STAGE(d ^ 1, (kt + 1) * 64);
    PJ_COMPUTE(d);
    __syncthreads();
    d ^= 1;
  }
  PJ_COMPUTE(d);

#pragma unroll
  for (int mt = 0; mt < 4; ++mt)
#pragma unroll
    for (int nt = 0; nt < 4; ++nt)
#pragma unroll
      for (int r = 0; r < 4; ++r)
        C[(size_t)(m0 + wm + mt * 16 + quad * 4 + r) * 1024 + n0 + wn + nt * 16 + l15] =
            (half_t)acc[mt][nt][r];
}

// ---------------- flash attention with Transformer-XL relative shift --------
// R15 version verbatim (92.0us proven): R8 structure, b-major qkv[B][T][2048],
// vT[1024][B*T] addressing.
__global__ __launch_bounds__(512, 4) void k_attn(const half_t* __restrict__ qkv,
                                                 const half_t* __restrict__ rbuf,
                                                 const half_t* __restrict__ vT,
                                                 const float* __restrict__ pbu,
                                                 const float* __restrict__ pbv,
                                                 half_t* __restrict__ av) {
  __shared__ __align__(16) half_t ldsK[64][64];        // [key][dh], XOR chunks
  __shared__ __align__(16) half_t ldsV[64][64];        // [dh][key], XOR chunks
  __shared__ __align__(16) half_t ldsR[256][64];       // r ring, XOR chunks
  __shared__ __align__(16) half_t ldsP[8][16][72];     // per-wave P (wave-internal)
  const int t = threadIdx.x;
  const int wave = t >> 6, lane = t & 63, quad = lane >> 4, l15 = lane & 15;

  // work-pairing swizzle: CU-co-resident blocks get x and 7-x
  const int li = blockIdx.x + 8 * blockIdx.y;
  const int c = li & 255, kr = li >> 8;
  const int xe = kr == 0 ? (c & 7) : 7 - (c & 7);
  const int bn = (c >> 3) + (kr << 5);
  const int i0 = xe * 128;
  const int b = bn >> 4, n = bn & 15;
  const int i_base = i0 + wave * 16;
  const int p0 = 896 - i0;  // global r-row of ring origin at tile 0

  // q fragments with biases folded in
  half8 qu[2], qv[2];
#pragma unroll
  for (int ks = 0; ks < 2; ++ks) {
    const int dh0 = ks * 32 + quad * 8;
    const half8 qf = *(const half8*)&qkv[((size_t)(b * 2048 + M_LEN + i_base + l15)) * 2048 + n * 64 + dh0];
#pragma unroll
    for (int j = 0; j < 8; ++j) {
      const float qj = (float)qf[j];
      qu[ks][j] = (half_t)(qj + pbu[n * 64 + dh0 + j]);
      qv[ks][j] = (half_t)(qj + pbv[n * 64 + dh0 + j]);
    }
  }

  // E-shift lane rotation constants (loop-invariant): score col cj reads
  // window col cj + 15 - irow; rotation is uniform within a quad per r.
  int bperm_idx[4];
  bool lo_sel[4];
#pragma unroll
  for (int r = 0; r < 4; ++r) {
    const int irow = quad * 4 + r;
    bperm_idx[r] = ((lane & 48) | ((l15 + 15 - irow) & 15)) << 2;
    lo_sel[r] = (l15 <= irow);  // true: window col in tile nt; false: nt+1
  }

  f32x4 oacc[4] = {};
  float lpart[4] = {0.f, 0.f, 0.f, 0.f};
  const float k1 = 0.125f * 1.44269504088896f;  // scale * log2(e)
  const float kC = -4.0f * 1.44269504088896f;   // -C * log2(e)

  // staging geometry (K/V and steady-state R: 512 thr cover 64 rows x 8 chunks)
  const int srow = t >> 3, sc3 = t & 7;
  const int sxk = (sc3 ^ (srow & 7)) * 8;

  const int ntile = xe * 2 + 18;

  // ---- prologue: K/V tile 0, R ring rows [p0, p0+255] (4 passes) ----
  half8 kreg = *(const half8*)&qkv[((size_t)(b * 2048 + srow)) * 2048 + 1024 + n * 64 + sc3 * 8];
  half8 vreg = *(const half8*)&vT[((size_t)(n * 64 + srow)) * 8192 + b * 2048 + sc3 * 8];
  half8 rreg4[4];
  int rr4[4], rc4[4];
#pragma unroll
  for (int i = 0; i < 4; ++i) {
    const int ci = t + 512 * i;
    rr4[i] = ci >> 3; rc4[i] = ci & 7;
    const int ps = p0 + rr4[i] > 2047 ? 2047 : p0 + rr4[i];
    rreg4[i] = *(const half8*)&rbuf[(size_t)ps * 1024 + n * 64 + rc4[i] * 8];
  }
  half8 rpre;  // steady-state prefetch reg

  for (int kt = 0; kt < ntile; ++kt) {
    const int j0 = kt * 64;

    __syncthreads();  // prev-iter LDS reads done; drains vmcnt -> regs ready
    *(half8*)&ldsK[srow][sxk] = kreg;
    *(half8*)&ldsV[srow][sxk] = vreg;
    if (kt == 0) {
#pragma unroll
      for (int i = 0; i < 4; ++i) {
        const int pg = p0 + rr4[i];
        *(half8*)&ldsR[pg & 255][(rc4[i] ^ (pg & 7)) * 8] = rreg4[i];
      }
    } else {
      const int pw = j0 + p0 + 192 + srow;  // rows loaded during tile kt-1
      *(half8*)&ldsR[pw & 255][(sc3 ^ (pw & 7)) * 8] = rpre;
    }
    __syncthreads();

    // ---- prefetch tile kt+1 (regs dead after the writes above) ----
    if (kt + 1 < ntile) {
      const int j0n = j0 + 64;
      kreg = *(const half8*)&qkv[((size_t)(b * 2048 + j0n + srow)) * 2048 + 1024 + n * 64 + sc3 * 8];
      vreg = *(const half8*)&vT[((size_t)(n * 64 + srow)) * 8192 + b * 2048 + j0n + sc3 * 8];
      const int pn = j0 + p0 + 256 + srow;  // new ring rows for tile kt+1
      const int pc = pn > 2047 ? 2047 : pn;
      rpre = *(const half8*)&rbuf[(size_t)pc * 1024 + n * 64 + sc3 * 8];
    }

    // ---- AC = (q+u) @ K^T ----
    f32x4 ac[4] = {};
#pragma unroll
    for (int ks = 0; ks < 2; ++ks)
#pragma unroll
      for (int nt = 0; nt < 4; ++nt) {
        const int row = nt * 16 + l15;
        const half8 kf = *(const half8*)&ldsK[row][((ks * 4 + quad) ^ (row & 7)) * 8];
        ac[nt] = __builtin_amdgcn_mfma_f32_16x16x32_f16(qu[ks], kf, ac[nt], 0, 0, 0);
      }

    // ---- E window: E[m][c] = (q+v) . r[window c], width 80 (ring reads) ----
    const int rbg = j0 + p0 + 112 - wave * 16;  // wave's window start (global)
    f32x4 ea[5] = {};
#pragma unroll
    for (int ks = 0; ks < 2; ++ks)
#pragma unroll
      for (int et = 0; et < 5; ++et) {
        const int pr = rbg + et * 16 + l15;
        const half8 rf = *(const half8*)&ldsR[pr & 255][((ks * 4 + quad) ^ (pr & 7)) * 8];
        ea[et] = __builtin_amdgcn_mfma_f32_16x16x32_f16(qv[ks], rf, ea[et], 0, 0, 0);
      }

    // ---- scores -> p; E shift via in-register bpermute (f32) ----
    const bool maskt = j0 > i_base + 960;
#pragma unroll
    for (int r = 0; r < 4; ++r) {
      const int irow = quad * 4 + r;
      const int ig = i_base + irow;
      float rot[5];
#pragma unroll
      for (int et = 0; et < 5; ++et)
        rot[et] = __int_as_float(
            __builtin_amdgcn_ds_bpermute(bperm_idx[r], __float_as_int(ea[et][r])));
      float psum = 0.f;
#pragma unroll
      for (int nt = 0; nt < 4; ++nt) {
        const float ev = lo_sel[r] ? rot[nt] : rot[nt + 1];
        const int cj = nt * 16 + l15;
        float p = __builtin_amdgcn_exp2f(fmaf(ac[nt][r] + ev, k1, kC));
        if (maskt && (j0 + cj > ig + M_LEN)) p = 0.f;
        psum += p;
        ldsP[wave][irow][cj] = (half_t)p;
      }
      lpart[r] += psum;
    }
    __builtin_amdgcn_wave_barrier();  // P round trip is wave-internal

    // ---- PV ----
    half8 pa[2];
#pragma unroll
    for (int ks = 0; ks < 2; ++ks)
      pa[ks] = *(const half8*)&ldsP[wave][l15][ks * 32 + quad * 8];
#pragma unroll
    for (int ks = 0; ks < 2; ++ks)
#pragma unroll
      for (int dnt = 0; dnt < 4; ++dnt) {
        const int row = dnt * 16 + l15;
        const half8 vf = *(const half8*)&ldsV[row][((ks * 4 + quad) ^ (row & 7)) * 8];
        oacc[dnt] = __builtin_amdgcn_mfma_f32_16x16x32_f16(pa[ks], vf, oacc[dnt], 0, 0, 0);
      }
  }

  // final l-sum reduction + normalize + store
#pragma unroll
  for (int r = 0; r < 4; ++r) {
    float l = lpart[r];
#pragma unroll
    for (int off = 1; off < 16; off <<= 1) l += __shfl_xor(l, off);
    const float inv = 1.0f / l;
    const int ig = i_base + quad * 4 + r;
#pragma unroll
    for (int dnt = 0; dnt < 4; ++dnt)
      av[((size_t)ig * BATCH + b) * 1024 + n * 64 + dnt * 16 + l15] = (half_t)(oacc[dnt][r] * inv);
  }
}

// -------- residual + LayerNorm (one block per row; sums 2 fp16 partials) ----
__global__ __launch_bounds__(256) void k_ln(const float* __restrict__ x,
                                            const half_t* __restrict__ ao0,
                                            const half_t* __restrict__ ao1,
                                            const float* __restrict__ gamma,
                                            const float* __restrict__ beta,
                                            float* __restrict__ out) {
  const int row = blockIdx.x;
  const int t = threadIdx.x;
  const float4 xv = ((const float4*)(x + (size_t)row * 1024))[t];
  const half4v a4 = ((const half4v*)(ao0 + (size_t)row * 1024))[t];
  const half4v b4 = ((const half4v*)(ao1 + (size_t)row * 1024))[t];
  const float y0 = xv.x + (float)a4[0] + (float)b4[0];
  const float y1 = xv.y + (float)a4[1] + (float)b4[1];
  const float y2 = xv.z + (float)a4[2] + (float)b4[2];
  const float y3 = xv.w + (float)a4[3] + (float)b4[3];
  float s = y0 + y1 + y2 + y3;
  float ss = y0 * y0 + y1 * y1 + y2 * y2 + y3 * y3;
#pragma unroll
  for (int off = 1; off < 64; off <<= 1) {
    s += __shfl_xor(s, off);
    ss += __shfl_xor(ss, off);
  }
  __shared__ float sb[4], ssb[4];
  if ((t & 63) == 0) { sb[t >> 6] = s; ssb[t >> 6] = ss; }
  __syncthreads();
  s = sb[0] + sb[1] + sb[2] + sb[3];
  ss = ssb[0] + ssb[1] + ssb[2] + ssb[3];
  const float mean = s * (1.f / 1024.f);
  const float var = ss * (1.f / 1024.f) - mean * mean;
  const float rstd = rsqrtf(var + 1e-5f);
  const float4 g = ((const float4*)gamma)[t];
  const float4 be = ((const float4*)beta)[t];
  float4 o;
  o.x = (y0 - mean) * rstd * g.x + be.x;
  o.y = (y1 - mean) * rstd * g.y + be.y;
  o.z = (y2 - mean) * rstd * g.z + be.z;
  o.w = (y3 - mean) * rstd * g.w + be.w;
  ((float4*)(out + (size_t)row * 1024))[t] = o;
}

// ---------------------------------------------------------------------------
extern "C" void kernel_launch(void* const* d_in, const int* in_sizes, int n_in,
                              void* d_out, int out_size, void* d_ws, size_t ws_size,
                              hipStream_t stream) {
  const float* x     = (const float*)d_in[0];
  const float* pos   = (const float*)d_in[1];
  const float* pbu   = (const float*)d_in[2];
  const float* pbv   = (const float*)d_in[3];
  const float* mem   = (const float*)d_in[4];
  const float* Wqkv  = (const float*)d_in[5];
  const float* Wrel  = (const float*)d_in[6];
  const float* Wo    = (const float*)d_in[7];
  const float* gamma = (const float*)d_in[8];
  const float* beta  = (const float*)d_in[9];
  float* out = (float*)d_out;

  half_t* ws    = (half_t*)d_ws;
  half_t* cbf   = ws;                 // [4][2048][1024] b-major
  half_t* posb  = cbf + 8388608;      // [2048][1024]
  half_t* wqkvT = posb + 2097152;     // [3072][1024]
  half_t* wrelT = wqkvT + 3145728;    // [1024][1024]
  half_t* woT   = wrelT + 1048576;    // [1024][1024]
  half_t* qkv   = woT + 1048576;      // [4][2048][2048] b-major (Q|K)
  half_t* rb    = qkv + 16777216;     // [2048][1024]
  half_t* vT    = rb + 2097152;       // [1024][4*2048]
  half_t* av    = vT + 8388608;       // [4096][1024]
  half_t* aout0 = qkv;                // reuse qkv region (partial 0)
  half_t* aout1 = qkv + 4194304;      // partial 1

  k_pre<<<11520, 256, 0, stream>>>(mem, x, pos, Wqkv, Wrel, Wo, cbf, posb, wqkvT, wrelT, woT);
  k_gemm_qkv_pos<<<416, 512, 0, stream>>>(cbf, wqkvT, qkv, posb, wrelT, rb, vT);
  k_attn<<<dim3(8, 64), 512, 0, stream>>>(qkv, rb, vT, pbu, pbv, av);
  k_gemm_proj<<<256, 512, 0, stream>>>(av, woT, aout0, aout1);
  k_ln<<<4096, 256, 0, stream>>>(x, aout0, aout1, gamma, beta, out);
}